// Round 1
// baseline (267.136 us; speedup 1.0000x reference)
//
#include <hip/hip_runtime.h>

#define N_NODES  100000
#define N_EDGES  1600000
#define IN_CH    128
#define HID      32
#define N_GRAPHS 64

#define NBIN   391            // bins of 256 dst nodes: bin = dst >> 8
#define CHUNK  4096           // edges per multisplit block; grid = 391
#define MGRID  391            // ceil(1.6M / 4096)
#define STG    5120           // csr2 per-bin staging capacity

// workspace layout (4-byte element offsets) — total ~26.4 MB
#define OFF_B      0          // Bu1: bf16 B, uint[1,600,000]; H[391*391] aliases head (dead before gemm1)
#define OFF_EDGEPK 3200000    // int[1,600,000]; Bu2 aliases after csr2
#define OFF_CSR    4800000    // int[1,600,000]
#define OFF_COLT   6400000    // int[391]
#define OFF_BINB   6400391    // int[392]
#define OFF_ROWPTR 6400784    // int[100,001]
#define OFF_DINV   6500785    // float[100,000]
#define OFF_GS     6600800    // float[64*32] gsum + float[64] cnt

// bf16 pack (RNE) / unpack helpers
__device__ __forceinline__ unsigned bfr(float f) {
    unsigned u = __float_as_uint(f);
    u += 0x7fffu + ((u >> 16) & 1u);
    return u >> 16;
}
__device__ __forceinline__ float bflo(unsigned w) { return __uint_as_float(w << 16); }
__device__ __forceinline__ float bfhi(unsigned w) { return __uint_as_float(w & 0xffff0000u); }

// ---------- phase 1: per-(bin, wg) histogram ----------
__global__ __launch_bounds__(512) void hist_kernel(const int* __restrict__ dst,
                                                   int* __restrict__ H) {
    __shared__ int s[512];
    int t = threadIdx.x, wg = blockIdx.x;
    s[t] = 0;
    __syncthreads();
    int e0 = wg * CHUNK, e1 = min(e0 + CHUNK, N_EDGES);
    for (int e = e0 + t; e < e1; e += 512) {
        int d = dst[e];
        if ((unsigned)d < N_NODES) atomicAdd(&s[d >> 8], 1);
    }
    __syncthreads();
    if (t < NBIN) H[t * MGRID + wg] = s[t];
}

// ---------- phase 2a ----------
__global__ __launch_bounds__(512) void scanrow_kernel(int* __restrict__ H,
                                                      int* __restrict__ colT) {
    __shared__ int s[512];
    int t = threadIdx.x, bin = blockIdx.x;
    s[t] = (t < MGRID) ? H[bin * MGRID + t] : 0;
    __syncthreads();
    for (int off = 1; off < 512; off <<= 1) {
        int v = (t >= off) ? s[t - off] : 0;
        __syncthreads();
        if (t >= off) s[t] += v;
        __syncthreads();
    }
    if (t < MGRID) H[bin * MGRID + t] = t ? s[t - 1] : 0;
    if (t == 0) colT[bin] = s[MGRID - 1];
}

// ---------- phase 2b ----------
__global__ __launch_bounds__(512) void scanbase_kernel(const int* __restrict__ colT,
                                                       int* __restrict__ binB,
                                                       int* __restrict__ row_ptr) {
    __shared__ int s[512];
    int t = threadIdx.x;
    s[t] = (t < NBIN) ? colT[t] : 0;
    __syncthreads();
    for (int off = 1; off < 512; off <<= 1) {
        int v = (t >= off) ? s[t - off] : 0;
        __syncthreads();
        if (t >= off) s[t] += v;
        __syncthreads();
    }
    if (t < NBIN) binB[t] = t ? s[t - 1] : 0;
    if (t == 0) { binB[NBIN] = s[NBIN - 1]; row_ptr[N_NODES] = s[NBIN - 1]; }
}

// ---------- phase 3: bin-grouped scatter, LDS-staged coalesced flush ----------
__global__ __launch_bounds__(512) void msplit_kernel(const int* __restrict__ src,
                                                     const int* __restrict__ dst,
                                                     const int* __restrict__ H,
                                                     const int* __restrict__ binB,
                                                     int* __restrict__ edgepk) {
    __shared__ int s[512];
    __shared__ int cur[NBIN];
    __shared__ int gb[NBIN];
    __shared__ int stage[CHUNK];
    __shared__ int gof[CHUNK];
    int t = threadIdx.x, wg = blockIdx.x;
    s[t] = 0;
    __syncthreads();
    int e0 = wg * CHUNK, e1 = min(e0 + CHUNK, N_EDGES);
    for (int e = e0 + t; e < e1; e += 512) {
        int d = dst[e];
        if ((unsigned)d < N_NODES) atomicAdd(&s[d >> 8], 1);
    }
    __syncthreads();
    for (int off = 1; off < 512; off <<= 1) {
        int v = (t >= off) ? s[t - off] : 0;
        __syncthreads();
        if (t >= off) s[t] += v;
        __syncthreads();
    }
    if (t < NBIN) {
        int lo = t ? s[t - 1] : 0;
        cur[t] = lo;
        gb[t] = binB[t] + H[t * MGRID + wg] - lo;
    }
    __syncthreads();
    for (int e = e0 + t; e < e1; e += 512) {
        int d = dst[e];
        if ((unsigned)d < N_NODES) {
            int b = d >> 8;
            int p = atomicAdd(&cur[b], 1);
            stage[p] = (src[e] << 8) | (d & 255);
            gof[p] = gb[b];
        }
    }
    __syncthreads();
    int total = s[511];
    for (int p = t; p < total; p += 512)
        edgepk[gof[p] + p] = stage[p];
}

// ---------- phase 4: within-bin reorder -> CSR + dinv/row_ptr ----------
__global__ __launch_bounds__(256) void csr2_kernel(const int* __restrict__ edgepk,
                                                   const int* __restrict__ binB,
                                                   int* __restrict__ row_ptr,
                                                   float* __restrict__ dinv,
                                                   int* __restrict__ csr) {
    __shared__ int cnt[256], s[256], cur[256];
    __shared__ int stage[STG];
    int t = threadIdx.x, bin = blockIdx.x;
    int ebase = binB[bin], eend = binB[bin + 1];
    int n = eend - ebase;
    cnt[t] = 0;
    __syncthreads();
    for (int p = ebase + t; p < eend; p += 256)
        atomicAdd(&cnt[edgepk[p] & 255], 1);
    __syncthreads();
    s[t] = cnt[t];
    __syncthreads();
    for (int off = 1; off < 256; off <<= 1) {
        int v = (t >= off) ? s[t - off] : 0;
        __syncthreads();
        if (t >= off) s[t] += v;
        __syncthreads();
    }
    int excl = t ? s[t - 1] : 0;
    int node = (bin << 8) + t;
    if (node < N_NODES) {
        dinv[node] = rsqrtf((float)(cnt[t] + 1));
        row_ptr[node] = ebase + excl;
    }
    cur[t] = excl;
    __syncthreads();
    for (int p = ebase + t; p < eend; p += 256) {
        int w = edgepk[p];
        int l = atomicAdd(&cur[w & 255], 1);
        int sv = w >> 8;
        if (l < STG) stage[l] = sv;
        else csr[ebase + l] = sv;
    }
    __syncthreads();
    int lim = min(n, STG);
    for (int l = t; l < lim; l += 256)
        csr[ebase + l] = stage[l];
}

// ---------- B(bf16) = (x @ W1) * dinv[row], register-tiled (4 ch/thread) ----------
#define XS1 132               // 128 + 4 pad
__global__ __launch_bounds__(256) void gemm1_kernel(const float* __restrict__ x,
                                                    const float* __restrict__ W1,
                                                    const float* __restrict__ dinv,
                                                    unsigned* __restrict__ Bu) {
    __shared__ float Wl[IN_CH * HID];   // 16 KB
    __shared__ float xs[32 * XS1];      // 16.9 KB
    int tid = threadIdx.x;
    for (int j = tid; j < IN_CH * HID / 4; j += 256)
        ((float4*)Wl)[j] = ((const float4*)W1)[j];
    int row0 = blockIdx.x * 32;         // 100000 % 32 == 0
    const float4* x4 = (const float4*)(x + (size_t)row0 * IN_CH);
    for (int j = tid; j < 32 * IN_CH / 4; j += 256) {
        int r = j >> 5, k4 = j & 31;
        ((float4*)&xs[r * XS1])[k4] = x4[j];
    }
    __syncthreads();
    int r = tid >> 3, cg = (tid & 7) * 4;
    const float* xr = &xs[r * XS1];
    float4 acc = {0.f, 0.f, 0.f, 0.f};
    #pragma unroll 8
    for (int k = 0; k < IN_CH; ++k) {
        float xv = xr[k];
        float4 w = *(const float4*)&Wl[k * HID + cg];
        acc.x += xv * w.x; acc.y += xv * w.y; acc.z += xv * w.z; acc.w += xv * w.w;
    }
    int row = row0 + r;
    float dv = dinv[row];
    uint2 p;
    p.x = bfr(acc.x * dv) | (bfr(acc.y * dv) << 16);
    p.y = bfr(acc.z * dv) | (bfr(acc.w * dv) << 16);
    *(uint2*)&Bu[(size_t)row * 16 + (tid & 7) * 2] = p;
}

// ---------- fused layer 1: gather + bias + relu, then (h1 @ W2)*dinv -> Bu2 ----------
// 16 lanes/node (2 ch each). h1 never touches HBM: staged in LDS, multiplied by
// LDS-resident W2 (32x32), bf16-packed directly into the layer-2 B buffer.
__global__ __launch_bounds__(256) void layer1_fused_kernel(const unsigned* __restrict__ Bu,
                                                           const int* __restrict__ csr,
                                                           const int* __restrict__ row_ptr,
                                                           const float* __restrict__ dinv,
                                                           const float* __restrict__ bias,
                                                           const float* __restrict__ W2,
                                                           unsigned* __restrict__ Bu2) {
    __shared__ float W2l[HID * HID];    // 4 KB
    __shared__ float hs[16 * 33];       // 2.1 KB, stride 33 breaks bank aliasing
    int tid = threadIdx.x;
    ((float4*)W2l)[tid] = ((const float4*)W2)[tid];   // 1024 floats / 256 thr
    int node = blockIdx.x * 16 + (tid >> 4);   // grid 6250 -> exactly 100000 nodes
    int c2 = tid & 15;
    unsigned ws0 = Bu[(size_t)node * 16 + c2];
    float a0 = bflo(ws0), a1 = bfhi(ws0);
    int j = row_ptr[node], re = row_ptr[node + 1];
    for (; j + 8 <= re; j += 8) {
        int s0 = csr[j + 0], s1 = csr[j + 1], s2 = csr[j + 2], s3 = csr[j + 3];
        int s4 = csr[j + 4], s5 = csr[j + 5], s6 = csr[j + 6], s7 = csr[j + 7];
        unsigned w0 = Bu[(size_t)s0 * 16 + c2], w1 = Bu[(size_t)s1 * 16 + c2];
        unsigned w2 = Bu[(size_t)s2 * 16 + c2], w3 = Bu[(size_t)s3 * 16 + c2];
        unsigned w4 = Bu[(size_t)s4 * 16 + c2], w5 = Bu[(size_t)s5 * 16 + c2];
        unsigned w6 = Bu[(size_t)s6 * 16 + c2], w7 = Bu[(size_t)s7 * 16 + c2];
        a0 += ((bflo(w0) + bflo(w1)) + (bflo(w2) + bflo(w3)))
            + ((bflo(w4) + bflo(w5)) + (bflo(w6) + bflo(w7)));
        a1 += ((bfhi(w0) + bfhi(w1)) + (bfhi(w2) + bfhi(w3)))
            + ((bfhi(w4) + bfhi(w5)) + (bfhi(w6) + bfhi(w7)));
    }
    if (j + 4 <= re) {
        int s0 = csr[j], s1 = csr[j + 1], s2 = csr[j + 2], s3 = csr[j + 3];
        unsigned w0 = Bu[(size_t)s0 * 16 + c2], w1 = Bu[(size_t)s1 * 16 + c2];
        unsigned w2 = Bu[(size_t)s2 * 16 + c2], w3 = Bu[(size_t)s3 * 16 + c2];
        a0 += (bflo(w0) + bflo(w1)) + (bflo(w2) + bflo(w3));
        a1 += (bfhi(w0) + bfhi(w1)) + (bfhi(w2) + bfhi(w3));
        j += 4;
    }
    for (; j < re; ++j) {
        unsigned w = Bu[(size_t)csr[j] * 16 + c2];
        a0 += bflo(w); a1 += bfhi(w);
    }
    float dv = dinv[node];
    float h0 = fmaxf(a0 * dv + bias[2 * c2], 0.f);
    float h1 = fmaxf(a1 * dv + bias[2 * c2 + 1], 0.f);
    int r = tid >> 4;
    hs[r * 33 + 2 * c2]     = h0;
    hs[r * 33 + 2 * c2 + 1] = h1;
    __syncthreads();
    const float* hr = &hs[r * 33];
    float o0 = 0.f, o1 = 0.f;
    #pragma unroll
    for (int k = 0; k < HID; ++k) {
        float hv = hr[k];                                   // broadcast within node group
        float2 w = *(const float2*)&W2l[k * HID + 2 * c2];  // conflict-free
        o0 += hv * w.x; o1 += hv * w.y;
    }
    Bu2[(size_t)node * 16 + c2] = bfr(o0 * dv) | (bfr(o1 * dv) << 16);
}

// ---------- fused layer 2: gather + bias -> h (output) + per-graph pool ----------
// batch is sorted, so a block's 16 nodes span [batch[n0], batch[n0+15]];
// accumulate in a small LDS pool, flush span*HID global atomics per block.
__global__ __launch_bounds__(256) void layer2_pool_kernel(const unsigned* __restrict__ Bu,
                                                          const int* __restrict__ csr,
                                                          const int* __restrict__ row_ptr,
                                                          const float* __restrict__ dinv,
                                                          const float* __restrict__ bias,
                                                          const int* __restrict__ batch,
                                                          float* __restrict__ out,
                                                          float* __restrict__ gsum,
                                                          float* __restrict__ cnt) {
    __shared__ float pl[N_GRAPHS * HID];   // worst-case span (sorted batch w/ gaps)
    __shared__ float pc[N_GRAPHS];
    int tid = threadIdx.x;
    int node0 = blockIdx.x * 16;
    int g0 = batch[node0];
    int span = batch[node0 + 15] - g0 + 1;     // typically 1-2
    for (int q = tid; q < span * HID; q += 256) pl[q] = 0.f;
    if (tid < span) pc[tid] = 0.f;
    int node = node0 + (tid >> 4);
    int c2 = tid & 15;
    unsigned ws0 = Bu[(size_t)node * 16 + c2];
    float a0 = bflo(ws0), a1 = bfhi(ws0);
    int j = row_ptr[node], re = row_ptr[node + 1];
    for (; j + 8 <= re; j += 8) {
        int s0 = csr[j + 0], s1 = csr[j + 1], s2 = csr[j + 2], s3 = csr[j + 3];
        int s4 = csr[j + 4], s5 = csr[j + 5], s6 = csr[j + 6], s7 = csr[j + 7];
        unsigned w0 = Bu[(size_t)s0 * 16 + c2], w1 = Bu[(size_t)s1 * 16 + c2];
        unsigned w2 = Bu[(size_t)s2 * 16 + c2], w3 = Bu[(size_t)s3 * 16 + c2];
        unsigned w4 = Bu[(size_t)s4 * 16 + c2], w5 = Bu[(size_t)s5 * 16 + c2];
        unsigned w6 = Bu[(size_t)s6 * 16 + c2], w7 = Bu[(size_t)s7 * 16 + c2];
        a0 += ((bflo(w0) + bflo(w1)) + (bflo(w2) + bflo(w3)))
            + ((bflo(w4) + bflo(w5)) + (bflo(w6) + bflo(w7)));
        a1 += ((bfhi(w0) + bfhi(w1)) + (bfhi(w2) + bfhi(w3)))
            + ((bfhi(w4) + bfhi(w5)) + (bfhi(w6) + bfhi(w7)));
    }
    if (j + 4 <= re) {
        int s0 = csr[j], s1 = csr[j + 1], s2 = csr[j + 2], s3 = csr[j + 3];
        unsigned w0 = Bu[(size_t)s0 * 16 + c2], w1 = Bu[(size_t)s1 * 16 + c2];
        unsigned w2 = Bu[(size_t)s2 * 16 + c2], w3 = Bu[(size_t)s3 * 16 + c2];
        a0 += (bflo(w0) + bflo(w1)) + (bflo(w2) + bflo(w3));
        a1 += (bfhi(w0) + bfhi(w1)) + (bfhi(w2) + bfhi(w3));
        j += 4;
    }
    for (; j < re; ++j) {
        unsigned w = Bu[(size_t)csr[j] * 16 + c2];
        a0 += bflo(w); a1 += bfhi(w);
    }
    float dv = dinv[node];
    float2 o;
    o.x = a0 * dv + bias[2 * c2];
    o.y = a1 * dv + bias[2 * c2 + 1];
    *(float2*)&out[(size_t)node * HID + 2 * c2] = o;
    int gl = batch[node] - g0;
    __syncthreads();                       // zeroing done before any atomic lands
    atomicAdd(&pl[gl * HID + 2 * c2], o.x);
    atomicAdd(&pl[gl * HID + 2 * c2 + 1], o.y);
    if (c2 == 0) atomicAdd(&pc[gl], 1.f);
    __syncthreads();
    for (int q = tid; q < span * HID; q += 256)
        atomicAdd(&gsum[g0 * HID + q], pl[q]);
    if (tid < span) atomicAdd(&cnt[g0 + tid], pc[tid]);
}

__global__ void summary_kernel(const float* __restrict__ gsum, const float* __restrict__ cnt,
                               const float* __restrict__ Ws, const float* __restrict__ bs,
                               float* __restrict__ out) {
    int g = blockIdx.x, c = threadIdx.x;
    float inv = 1.f / fmaxf(cnt[g], 1.f);
    float acc = bs[c];
    #pragma unroll
    for (int k = 0; k < HID; ++k)
        acc += gsum[g * HID + k] * inv * Ws[k * HID + c];
    out[g * HID + c] = acc;
}

extern "C" void kernel_launch(void* const* d_in, const int* in_sizes, int n_in,
                              void* d_out, int out_size, void* d_ws, size_t ws_size,
                              hipStream_t stream) {
    const float* x    = (const float*)d_in[0];
    const int* edge   = (const int*)d_in[1];
    const int* src    = edge;
    const int* dst    = edge + N_EDGES;
    const int* batch  = (const int*)d_in[2];
    const float* W1   = (const float*)d_in[3];
    const float* b1   = (const float*)d_in[4];
    const float* W2   = (const float*)d_in[5];
    const float* b2   = (const float*)d_in[6];
    const float* Ws   = (const float*)d_in[7];
    const float* bs   = (const float*)d_in[8];

    float* ws      = (float*)d_ws;
    unsigned* Bu1  = (unsigned*)(ws + OFF_B);     // layer-1 B; H aliases head (dead before gemm1)
    unsigned* Bu2  = (unsigned*)(ws + OFF_EDGEPK);// layer-2 B; aliases edgepk (dead after csr2)
    int*   H       = (int*)(ws + OFF_B);
    int*   edgepk  = (int*)(ws + OFF_EDGEPK);
    int*   csr     = (int*)(ws + OFF_CSR);
    int*   colT    = (int*)(ws + OFF_COLT);
    int*   binB    = (int*)(ws + OFF_BINB);
    int*   row_ptr = (int*)(ws + OFF_ROWPTR);
    float* dinv    = ws + OFF_DINV;
    float* gsum    = ws + OFF_GS;
    float* cnt     = gsum + N_GRAPHS * HID;

    float* out     = (float*)d_out;
    float* out_sum = out;
    float* out_h   = out + N_GRAPHS * HID;

    // CSR build
    hist_kernel    <<<MGRID, 512, 0, stream>>>(dst, H);
    scanrow_kernel <<<NBIN,  512, 0, stream>>>(H, colT);
    scanbase_kernel<<<1,     512, 0, stream>>>(colT, binB, row_ptr);
    msplit_kernel  <<<MGRID, 512, 0, stream>>>(src, dst, H, binB, edgepk);
    csr2_kernel    <<<NBIN,  256, 0, stream>>>(edgepk, binB, row_ptr, dinv, csr);

    // layer 1 (B from x@W1), fused with gemm2 epilogue -> Bu2
    gemm1_kernel<<<N_NODES / 32, 256, 0, stream>>>(x, W1, dinv, Bu1);
    hipMemsetAsync(gsum, 0, (N_GRAPHS * HID + N_GRAPHS) * sizeof(float), stream);
    layer1_fused_kernel<<<N_NODES / 16, 256, 0, stream>>>(Bu1, csr, row_ptr, dinv, b1, W2, Bu2);

    // layer 2 fused with mean-pool accumulation
    layer2_pool_kernel<<<N_NODES / 16, 256, 0, stream>>>(Bu2, csr, row_ptr, dinv, b2, batch,
                                                         out_h, gsum, cnt);
    summary_kernel<<<N_GRAPHS, HID, 0, stream>>>(gsum, cnt, Ws, bs, out_sum);
}